// Round 3
// baseline (94.947 us; speedup 1.0000x reference)
//
#include <hip/hip_runtime.h>
#include <math.h>

#define EEG_CH 64
#define WIN    128
#define ROWP   132          // padded row stride (floats), keeps float2 reads 8B-aligned
#define NROWS  66
#define KW     9
#define OUTW   120          // 128 - 9 + 1
#define NOUT   10
#define NH     2

__device__ __forceinline__ float readlane_f(float v, int l) {
    return __int_as_float(__builtin_amdgcn_readlane(__float_as_int(v), l));
}

__launch_bounds__(1024)
__global__ void cnn_fused(const float* __restrict__ xg,
                          const float* __restrict__ w1g, const float* __restrict__ b1g,
                          const float* __restrict__ w2g, const float* __restrict__ b2g,
                          const float* __restrict__ cwg, const float* __restrict__ cbg,
                          const float* __restrict__ f1w, const float* __restrict__ f1b,
                          const float* __restrict__ f2w, const float* __restrict__ f2b,
                          float* __restrict__ out)
{
    __shared__ float xl[NROWS * ROWP];   // 66*132*4 = 34.8 KB
    __shared__ float rnorm[NROWS];
    __shared__ float nums[2];
    __shared__ float eeg_r_l[128];       // (2,64)
    __shared__ float hl[128];
    __shared__ float se_flat[128];
    __shared__ float msum[NOUT * NH];    // [o][h] means

    const int tid  = threadIdx.x;
    const int ws   = tid >> 6;
    const int lane = tid & 63;

    // ---- Phase A: stage x into LDS (row-padded), float4 both sides ----
    for (int t = tid; t < NROWS * (WIN / 4); t += 1024) {
        const int row = t >> 5, c4 = t & 31;
        const float4 v = *(const float4*)(xg + row * WIN + c4 * 4);
        *(float4*)(xl + row * ROWP + c4 * 4) = v;
    }

    // ---- Pre-load conv weights per lane (lane l <-> channel i=l), overlap with staging ----
    // cw[o][i][k] = cwg[o*576 + i*9 + k]; wave o holds channel l's 9 taps in VGPRs.
    const int wu = __builtin_amdgcn_readfirstlane(ws);   // wave-uniform wave id
    float wl[KW];
    if (wu < NOUT) {
        const float* __restrict__ cwo = cwg + wu * EEG_CH * KW + lane * KW;
        #pragma unroll
        for (int k = 0; k < KW; ++k) wl[k] = cwo[k];
    }
    __syncthreads();

    // ---- Phase B: row norms + the two scalar numerators ----
    for (int row = ws; row < NROWS; row += 16) {
        float v0 = xl[row * ROWP + lane];
        float v1 = xl[row * ROWP + 64 + lane];
        float s  = v0 * v0 + v1 * v1;
        for (int off = 32; off > 0; off >>= 1) s += __shfl_xor(s, off, 64);
        if (lane == 0) rnorm[row] = sqrtf(s);
    }
    if (ws < 2) {
        const int wrow = (ws == 0) ? 0 : 65;
        float p = xl[ROWP + lane]      * xl[wrow * ROWP + lane]
                + xl[ROWP + 64 + lane] * xl[wrow * ROWP + 64 + lane];
        for (int off = 32; off > 0; off >>= 1) p += __shfl_xor(p, off, 64);
        if (lane == 0) nums[ws] = p;
    }
    __syncthreads();

    // ---- Phases C/D/E: 2 waves (r = ws), intra-wave LDS deps only ----
    if (ws < 2) {
        const int r = ws, j = lane;
        {
            const float denom = rnorm[j + 1] * (r == 0 ? rnorm[0] : rnorm[65]);
            eeg_r_l[r * 64 + j] = nums[r] / denom;
        }
        {
            float acc = b1g[j];
            const float4* wr = (const float4*)(w1g + j * 64);
            const float4* er = (const float4*)(eeg_r_l + r * 64);
            #pragma unroll
            for (int i = 0; i < 16; ++i) {
                const float4 a = er[i], b = wr[i];
                acc += a.x * b.x + a.y * b.y + a.z * b.z + a.w * b.w;
            }
            hl[r * 64 + j] = tanhf(acc);
        }
        {
            float acc = b2g[j];
            const float4* wr = (const float4*)(w2g + j * 64);
            const float4* hr = (const float4*)(hl + r * 64);
            #pragma unroll
            for (int i = 0; i < 16; ++i) {
                const float4 a = hr[i], b = wr[i];
                acc += a.x * b.x + a.y * b.y + a.z * b.z + a.w * b.w;
            }
            float sg = 1.0f / (1.0f + expf(-acc));
            float mx = sg;
            for (int off = 32; off > 0; off >>= 1) mx = fmaxf(mx, __shfl_xor(mx, off, 64));
            float e = expf(sg - mx);
            float ss = e;
            for (int off = 32; off > 0; off >>= 1) ss += __shfl_xor(ss, off, 64);
            se_flat[r * 64 + j] = e / ss;
        }
    }
    __syncthreads();

    // ---- Phase F: conv + relu + mean; one wave per o; weights/se via readlane ----
    if (wu < NOUT) {
        const int o = wu;
        // per-lane se scales for channel l (read once; broadcast via readlane in-loop)
        const float s0l = se_flat[lane];
        const float s1l = se_flat[64 + lane];
        const int wbase = (lane < 60) ? 2 * lane : 116;   // lanes 60-63 redundant
        float a00 = 0.f, a01 = 0.f, a10 = 0.f, a11 = 0.f; // [h][w0/w1]

        #pragma unroll 4
        for (int i = 0; i < EEG_CH; ++i) {
            // 10-float window via aligned float2 LDS reads (merge to ds_read2_b64)
            const float2* xp = (const float2*)(xl + (i + 1) * ROWP + wbase);
            const float2 x0 = xp[0], x1 = xp[1], x2 = xp[2], x3 = xp[3], x4 = xp[4];
            const float xw[10] = { x0.x, x0.y, x1.x, x1.y, x2.x, x2.y,
                                   x3.x, x3.y, x4.x, x4.y };
            // broadcast channel i's taps + scales from lane i (pure VALU, no lgkm)
            float wk[KW];
            #pragma unroll
            for (int k = 0; k < KW; ++k) wk[k] = readlane_f(wl[k], i);
            const float s0 = readlane_f(s0l, i);
            const float s1 = readlane_f(s1l, i);

            float p0 = 0.f, p1 = 0.f;
            #pragma unroll
            for (int k = 0; k < KW; ++k) {
                p0 += xw[k]     * wk[k];
                p1 += xw[k + 1] * wk[k];
            }
            a00 += s0 * p0;  a01 += s0 * p1;
            a10 += s1 * p0;  a11 += s1 * p1;
        }

        const float bo = cbg[o];
        float r0 = fmaxf(a00 + bo, 0.f) + fmaxf(a01 + bo, 0.f);  // h=0
        float r1 = fmaxf(a10 + bo, 0.f) + fmaxf(a11 + bo, 0.f);  // h=1
        if (lane >= 60) { r0 = 0.f; r1 = 0.f; }
        for (int off = 32; off > 0; off >>= 1) {
            r0 += __shfl_xor(r0, off, 64);
            r1 += __shfl_xor(r1, off, 64);
        }
        if (lane == 0) {
            msum[o * NH + 0] = r0 * (1.0f / OUTW);
            msum[o * NH + 1] = r1 * (1.0f / OUTW);
        }
    }
    __syncthreads();

    // ---- Phase G: FCN 20 -> 10 -> 2 + softmax, wave 0 ----
    if (ws == 0) {
        float h2v = 0.f;
        if (lane < 10) {
            float a = f1b[lane];
            #pragma unroll
            for (int p = 0; p < 20; ++p) a += msum[p] * f1w[lane * 20 + p];
            h2v = 1.0f / (1.0f + expf(-a));
        }
        float t0 = (lane < 10) ? h2v * f2w[lane]      : 0.f;
        float t1 = (lane < 10) ? h2v * f2w[10 + lane] : 0.f;
        for (int off = 32; off > 0; off >>= 1) {
            t0 += __shfl_xor(t0, off, 64);
            t1 += __shfl_xor(t1, off, 64);
        }
        if (lane == 0) {
            const float l0 = f2b[0] + t0, l1 = f2b[1] + t1;
            const float m  = fmaxf(l0, l1);
            const float e0 = expf(l0 - m), e1 = expf(l1 - m);
            out[0] = e0 / (e0 + e1);
            out[1] = e1 / (e0 + e1);
        }
    }
}

extern "C" void kernel_launch(void* const* d_in, const int* in_sizes, int n_in,
                              void* d_out, int out_size, void* d_ws, size_t ws_size,
                              hipStream_t stream) {
    (void)in_sizes; (void)n_in; (void)d_ws; (void)ws_size; (void)out_size;
    const float* xg  = (const float*)d_in[0];
    const float* w1  = (const float*)d_in[1];
    const float* b1  = (const float*)d_in[2];
    const float* w2  = (const float*)d_in[3];
    const float* b2  = (const float*)d_in[4];
    const float* cw  = (const float*)d_in[5];
    const float* cb  = (const float*)d_in[6];
    const float* f1w = (const float*)d_in[7];
    const float* f1b = (const float*)d_in[8];
    const float* f2w = (const float*)d_in[9];
    const float* f2b = (const float*)d_in[10];
    float* out = (float*)d_out;
    cnn_fused<<<dim3(1), dim3(1024), 0, stream>>>(xg, w1, b1, w2, b2, cw, cb,
                                                  f1w, f1b, f2w, f2b, out);
}

// Round 4
// 88.530 us; speedup vs baseline: 1.0725x; 1.0725x over previous
//
#include <hip/hip_runtime.h>
#include <math.h>

#define EEG_CH 64
#define WIN    128
#define KW     9
#define OUTW   120
#define NOUT   10
#define ROWP   132          // padded LDS row stride for k2 (8B-aligned even-w float2s)

// d_ws layout (floats): [0..127] se_flat ([h][i]), [128..147] msum ([o][h])
#define WS_SE   0
#define WS_MSUM 128

__device__ __forceinline__ float readlane_f(float v, int l) {
    return __int_as_float(__builtin_amdgcn_readlane(__float_as_int(v), l));
}

// ---------------- k1: cosine features + SE MLP -> se_flat in d_ws ----------------
__launch_bounds__(1024)
__global__ void cnn_k1(const float* __restrict__ xg,
                       const float* __restrict__ w1g, const float* __restrict__ b1g,
                       const float* __restrict__ w2g, const float* __restrict__ b2g,
                       float* __restrict__ wsout)
{
    __shared__ float w1l[64 * 64];   // transposed: w1l[i*64+j] = w1g[j*64+i]
    __shared__ float w2l[64 * 64];
    __shared__ float rnorm[66];
    __shared__ float nums[2];

    const int tid  = threadIdx.x;
    const int wv   = tid >> 6;
    const int lane = tid & 63;

    if (wv >= 8) {
        // waves 8-15: stage w1/w2 transposed into LDS (overlaps phase B)
        const bool second = (wv >= 12);
        const float* __restrict__ src = second ? w2g : w1g;
        float* __restrict__ dst = second ? w2l : w1l;
        const int t0 = (wv & 3) * 64 + lane;          // 0..255 within group
        for (int t = t0; t < 1024; t += 256) {        // 1024 float4 tasks
            const int j  = t & 63;
            const int i4 = t >> 6;
            const float4 v = *(const float4*)(src + j * 64 + i4 * 4);
            dst[(i4 * 4 + 0) * 64 + j] = v.x;
            dst[(i4 * 4 + 1) * 64 + j] = v.y;
            dst[(i4 * 4 + 2) * 64 + j] = v.z;
            dst[(i4 * 4 + 3) * 64 + j] = v.w;
        }
    } else {
        // waves 0-7: row norms straight from global (coalesced)
        for (int row = wv; row < 66; row += 8) {
            const float v0 = xg[row * WIN + lane];
            const float v1 = xg[row * WIN + 64 + lane];
            float s = v0 * v0 + v1 * v1;
            for (int off = 32; off > 0; off >>= 1) s += __shfl_xor(s, off, 64);
            if (lane == 0) rnorm[row] = sqrtf(s);
        }
        if (wv < 2) {
            const int wrow = (wv == 0) ? 0 : 65;
            float p = xg[WIN + lane]      * xg[wrow * WIN + lane]
                    + xg[WIN + 64 + lane] * xg[wrow * WIN + 64 + lane];
            for (int off = 32; off > 0; off >>= 1) p += __shfl_xor(p, off, 64);
            if (lane == 0) nums[wv] = p;
        }
    }
    __syncthreads();

    if (wv < 2) {
        const int r = wv, j = lane;
        // C: cosine feature (lane j holds eeg_r[r][j])
        const float er = nums[r] / (rnorm[j + 1] * (r == 0 ? rnorm[0] : rnorm[65]));
        // D: h = tanh(eeg_r @ w1^T + b1); w1 from transposed LDS (conflict-free)
        float acc = b1g[j];
        #pragma unroll
        for (int i = 0; i < 64; ++i)
            acc += readlane_f(er, i) * w1l[i * 64 + j];
        const float hv = tanhf(acc);
        // E: se = softmax(sigmoid(h @ w2^T + b2), axis=1)
        float acc2 = b2g[j];
        #pragma unroll
        for (int i = 0; i < 64; ++i)
            acc2 += readlane_f(hv, i) * w2l[i * 64 + j];
        const float sg = 1.f / (1.f + expf(-acc2));
        float mx = sg;
        for (int off = 32; off > 0; off >>= 1) mx = fmaxf(mx, __shfl_xor(mx, off, 64));
        const float e = expf(sg - mx);
        float ss = e;
        for (int off = 32; off > 0; off >>= 1) ss += __shfl_xor(ss, off, 64);
        wsout[WS_SE + r * 64 + j] = e / ss;
    }
}

// ---------------- k2: conv + relu + mean, one block per output channel ----------------
__launch_bounds__(256)
__global__ void cnn_k2(const float* __restrict__ xg,
                       const float* __restrict__ cwg, const float* __restrict__ cbg,
                       float* __restrict__ wsio)
{
    __shared__ float xl[64 * ROWP];   // eeg rows 0..63 (x rows 1..64), padded
    __shared__ float part[4][OUTW];   // per-wave partial pre-relu sums

    const int tid  = threadIdx.x;
    const int wv   = tid >> 6;        // 0..3 = (h, ihalf)
    const int lane = tid & 63;
    const int o    = blockIdx.x;

    // stage eeg rows into LDS (64*32 float4 tasks)
    for (int t = tid; t < 2048; t += 256) {
        const int row = t >> 5, c4 = t & 31;
        const float4 v = *(const float4*)(xg + (row + 1) * WIN + c4 * 4);
        *(float4*)(xl + row * ROWP + c4 * 4) = v;
    }

    // lane-resident weights + se for this wave's 32-channel chunk
    const int h = wv >> 1, ihalf = wv & 1;
    const int chbase = ihalf * 32;
    float wl[KW];
    float sl = 0.f;
    if (lane < 32) {
        const float* __restrict__ cwo = cwg + o * (EEG_CH * KW) + (chbase + lane) * KW;
        #pragma unroll
        for (int k = 0; k < KW; ++k) wl[k] = cwo[k];
        sl = wsio[WS_SE + h * 64 + chbase + lane];
    }
    __syncthreads();

    const int wbase = (lane < 60) ? 2 * lane : 116;   // lanes 60-63 redundant
    float q0 = 0.f, q1 = 0.f;
    #pragma unroll 4
    for (int ii = 0; ii < 32; ++ii) {
        const int i = chbase + ii;
        const float2* xp = (const float2*)(xl + i * ROWP + wbase);
        const float2 x0 = xp[0], x1 = xp[1], x2 = xp[2], x3 = xp[3], x4 = xp[4];
        const float xw[10] = { x0.x, x0.y, x1.x, x1.y, x2.x, x2.y,
                               x3.x, x3.y, x4.x, x4.y };
        float wk[KW];
        #pragma unroll
        for (int k = 0; k < KW; ++k) wk[k] = readlane_f(wl[k], ii);
        const float s = readlane_f(sl, ii);
        float p0 = 0.f, p1 = 0.f;
        #pragma unroll
        for (int k = 0; k < KW; ++k) {
            p0 += xw[k]     * wk[k];
            p1 += xw[k + 1] * wk[k];
        }
        q0 += s * p0;
        q1 += s * p1;
    }
    if (lane < 60) {
        *(float2*)(&part[wv][wbase]) = make_float2(q0, q1);
    }
    __syncthreads();

    // waves 0,1 finalize h=0,1: add halves, +bias, relu, mean
    if (wv < 2) {
        const float bo = cbg[o];
        float r = 0.f;
        if (lane < 60) {
            const float v0 = part[wv * 2][wbase]     + part[wv * 2 + 1][wbase]     + bo;
            const float v1 = part[wv * 2][wbase + 1] + part[wv * 2 + 1][wbase + 1] + bo;
            r = fmaxf(v0, 0.f) + fmaxf(v1, 0.f);
        }
        for (int off = 32; off > 0; off >>= 1) r += __shfl_xor(r, off, 64);
        if (lane == 0) wsio[WS_MSUM + o * 2 + wv] = r * (1.0f / OUTW);
    }
}

// ---------------- k3: FCN 20 -> 10 -> 2 + softmax ----------------
__launch_bounds__(64)
__global__ void cnn_k3(const float* __restrict__ wsin,
                       const float* __restrict__ f1w, const float* __restrict__ f1b,
                       const float* __restrict__ f2w, const float* __restrict__ f2b,
                       float* __restrict__ out)
{
    const int lane = threadIdx.x;
    float h2v = 0.f;
    if (lane < 10) {
        float a = f1b[lane];
        #pragma unroll
        for (int p = 0; p < 20; ++p) a += wsin[WS_MSUM + p] * f1w[lane * 20 + p];
        h2v = 1.f / (1.f + expf(-a));
    }
    float t0 = (lane < 10) ? h2v * f2w[lane]      : 0.f;
    float t1 = (lane < 10) ? h2v * f2w[10 + lane] : 0.f;
    for (int off = 32; off > 0; off >>= 1) {
        t0 += __shfl_xor(t0, off, 64);
        t1 += __shfl_xor(t1, off, 64);
    }
    if (lane == 0) {
        const float l0 = f2b[0] + t0, l1 = f2b[1] + t1;
        const float m  = fmaxf(l0, l1);
        const float e0 = expf(l0 - m), e1 = expf(l1 - m);
        out[0] = e0 / (e0 + e1);
        out[1] = e1 / (e0 + e1);
    }
}

extern "C" void kernel_launch(void* const* d_in, const int* in_sizes, int n_in,
                              void* d_out, int out_size, void* d_ws, size_t ws_size,
                              hipStream_t stream) {
    (void)in_sizes; (void)n_in; (void)ws_size; (void)out_size;
    const float* xg  = (const float*)d_in[0];
    const float* w1  = (const float*)d_in[1];
    const float* b1  = (const float*)d_in[2];
    const float* w2  = (const float*)d_in[3];
    const float* b2  = (const float*)d_in[4];
    const float* cw  = (const float*)d_in[5];
    const float* cb  = (const float*)d_in[6];
    const float* f1w = (const float*)d_in[7];
    const float* f1b = (const float*)d_in[8];
    const float* f2w = (const float*)d_in[9];
    const float* f2b = (const float*)d_in[10];
    float* out = (float*)d_out;
    float* wsf = (float*)d_ws;

    cnn_k1<<<dim3(1),    dim3(1024), 0, stream>>>(xg, w1, b1, w2, b2, wsf);
    cnn_k2<<<dim3(NOUT), dim3(256),  0, stream>>>(xg, cw, cb, wsf);
    cnn_k3<<<dim3(1),    dim3(64),   0, stream>>>(wsf, f1w, f1b, f2w, f2b, out);
}